// Round 2
// baseline (156.128 us; speedup 1.0000x reference)
//
#include <hip/hip_runtime.h>
#include <cmath>

#define NEG_INF (-1.0e30f)

static constexpr int B = 256;
static constexpr int N = 65536;
static constexpr int CHUNKS = 4;                        // blocks per row
static constexpr int THREADS = 512;                     // 8 waves per block
static constexpr int NBLOCKS = B * CHUNKS;              // 1024
static constexpr int CHUNK_ELEMS = N / CHUNKS;          // 16384
static constexpr int ITER = CHUNK_ELEMS / 4 / THREADS;  // 8 float4 per thread
static constexpr float C_OFF = 40.96f;                  // 64*0.8^2 upper bound of both logits
static constexpr float CAND_THRESH = 0.98f;
static constexpr int CAP = 1024;                        // LDS candidate capacity
static constexpr int PSTRIDE = 16;                      // floats per block partial

__device__ __forceinline__ float wave_sum_f(float v) {
#pragma unroll
  for (int off = 32; off >= 1; off >>= 1) v += __shfl_xor(v, off, 64);
  return v;
}
__device__ __forceinline__ int wave_sum_i(int v) {
#pragma unroll
  for (int off = 32; off >= 1; off >>= 1) v += __shfl_xor(v, off, 64);
  return v;
}

// sorted-descending top-10 insert into t[0..9] (t[10..15] pad)
__device__ __forceinline__ void insert10(float t[16], float s) {
  if (s > t[9]) {
    t[9] = s;
#pragma unroll
    for (int i = 9; i > 0; --i) {
      float a = t[i - 1], b = t[i];
      t[i - 1] = fmaxf(a, b);
      t[i] = fminf(a, b);
    }
  }
}

// Merge this lane's descending-sorted 16-list with XOR-partner lane's list,
// keeping top-16 of the union (bitonic top-k merge).
__device__ __forceinline__ void merge_lists_shfl(float t[16], int off) {
  float b[16];
#pragma unroll
  for (int i = 0; i < 16; ++i) b[i] = __shfl_xor(t[i], off, 64);
  float c[16];
#pragma unroll
  for (int i = 0; i < 16; ++i) c[i] = fmaxf(t[i], b[15 - i]);
#pragma unroll
  for (int s = 8; s >= 1; s >>= 1) {
#pragma unroll
    for (int i = 0; i < 16; ++i) {
      if ((i & s) == 0) {
        float lo = c[i], hi = c[i + s];
        c[i] = fmaxf(lo, hi);
        c[i + s] = fminf(lo, hi);
      }
    }
  }
#pragma unroll
  for (int i = 0; i < 16; ++i) t[i] = c[i];
}

__device__ __forceinline__ void proc(float s, float l, float& s_p, float& s_n,
                                     int& nn, float* cand, int* cnt) {
  const bool pos = l > 0.5f;
  const bool neg = l < 0.25f;
  // d = pos ? (0.8-s) : (s-0.2); e = exp(64*relu(d)^2 - C). e is only
  // consumed when pos||neg, so junk e for masked lanes is harmless.
  float d = pos ? (0.8f - s) : (s - 0.2f);
  float r = fmaxf(d, 0.f);
  float e = __expf(fmaf(64.f * r, r, -C_OFF));
  if (pos) s_p += e;
  if (neg) {
    s_n += e;
    ++nn;
    if (s > CAND_THRESH) {
      int p = atomicAdd(cnt, 1);
      if (p < CAP) cand[p] = s;
    }
  }
}

__global__ void __launch_bounds__(THREADS, 8) ranking_partial_kernel(
    const float* __restrict__ sim, const float* __restrict__ label,
    float* __restrict__ partials) {
  const int blk = blockIdx.x;
  const int row = blk >> 2;
  const int chunk = blk & 3;
  const int tid = threadIdx.x;
  const int wave = tid >> 6, lane = tid & 63;

  __shared__ float cand[CAP];
  __shared__ int cnt;
  __shared__ float ls_p[8], ls_n[8];
  __shared__ int ls_c[8];
  __shared__ float ltop[8][16];
  if (tid == 0) cnt = 0;
  __syncthreads();

  const size_t base4 =
      (size_t)row * (N / 4) + (size_t)chunk * (CHUNK_ELEMS / 4);
  const float4* sim4 = reinterpret_cast<const float4*>(sim) + base4;
  const float4* lab4 = reinterpret_cast<const float4*>(label) + base4;

  float s_p = 0.f, s_n = 0.f;
  int nn = 0;

#pragma unroll 2
  for (int it = 0; it < ITER; ++it) {
    float4 sv = sim4[it * THREADS + tid];
    float4 lv = lab4[it * THREADS + tid];
    proc(sv.x, lv.x, s_p, s_n, nn, cand, &cnt);
    proc(sv.y, lv.y, s_p, s_n, nn, cand, &cnt);
    proc(sv.z, lv.z, s_p, s_n, nn, cand, &cnt);
    proc(sv.w, lv.w, s_p, s_n, nn, cand, &cnt);
  }

  s_p = wave_sum_f(s_p);
  s_n = wave_sum_f(s_n);
  nn = wave_sum_i(nn);
  if (lane == 0) {
    ls_p[wave] = s_p;
    ls_n[wave] = s_n;
    ls_c[wave] = nn;
  }
  __syncthreads();

  // block totals (every thread computes; cheap)
  float sp_tot = 0.f, sn_tot = 0.f;
  int nn_tot = 0;
#pragma unroll
  for (int i = 0; i < 8; ++i) {
    sp_tot += ls_p[i];
    sn_tot += ls_n[i];
    nn_tot += ls_c[i];
  }
  const int cnt_tot = cnt;
  // fallback needed if candidate set provably may not contain the chunk's
  // top-10 negatives: overflow, or fewer than 10 candidates while more
  // negatives exist below the threshold.
  const bool bad = (cnt_tot > CAP) || (cnt_tot < 10 && cnt_tot < nn_tot);

  float t[16];
#pragma unroll
  for (int i = 0; i < 16; ++i) t[i] = NEG_INF;

  float* P = partials + (size_t)blk * PSTRIDE;

  if (!bad) {
    if (wave == 0) {
      const int c = cnt_tot < CAP ? cnt_tot : CAP;
      for (int i = lane; i < c; i += 64) insert10(t, cand[i]);
#pragma unroll
      for (int off = 1; off < 64; off <<= 1) merge_lists_shfl(t, off);
      if (lane == 0) {
        P[0] = sp_tot;
        P[1] = sn_tot;
        P[2] = (float)nn_tot;
        P[3] = 0.f;
#pragma unroll
        for (int i = 0; i < 10; ++i) P[4 + i] = t[i];
      }
    }
  } else {
    // exact rescan of this chunk (block-uniform branch; L2/L3-hot re-read)
    for (int it = 0; it < ITER; ++it) {
      float4 sv = sim4[it * THREADS + tid];
      float4 lv = lab4[it * THREADS + tid];
      if (lv.x < 0.25f) insert10(t, sv.x);
      if (lv.y < 0.25f) insert10(t, sv.y);
      if (lv.z < 0.25f) insert10(t, sv.z);
      if (lv.w < 0.25f) insert10(t, sv.w);
    }
#pragma unroll
    for (int off = 1; off < 64; off <<= 1) merge_lists_shfl(t, off);
    if (lane == 0) {
#pragma unroll
      for (int i = 0; i < 16; ++i) ltop[wave][i] = t[i];
    }
    __syncthreads();
    if (wave == 0) {
      float m[16];
      if (lane < 8) {
#pragma unroll
        for (int i = 0; i < 16; ++i) m[i] = ltop[lane][i];
      } else {
#pragma unroll
        for (int i = 0; i < 16; ++i) m[i] = NEG_INF;
      }
      merge_lists_shfl(m, 1);
      merge_lists_shfl(m, 2);
      merge_lists_shfl(m, 4);
      if (lane == 0) {
        P[0] = sp_tot;
        P[1] = sn_tot;
        P[2] = (float)nn_tot;
        P[3] = 0.f;
#pragma unroll
        for (int i = 0; i < 10; ++i) P[4 + i] = m[i];
      }
    }
  }
}

__global__ void __launch_bounds__(256) final_kernel(
    const float* __restrict__ partials, float* __restrict__ out) {
  const int r = threadIdx.x;  // one row per thread, 256 rows
  float sp = 0.f, sn = 0.f, nnf = 0.f;
  float t[16];
#pragma unroll
  for (int i = 0; i < 16; ++i) t[i] = NEG_INF;
#pragma unroll
  for (int c = 0; c < CHUNKS; ++c) {
    const float* P = partials + (size_t)(r * CHUNKS + c) * PSTRIDE;
    sp += P[0];
    sn += P[1];
    nnf += P[2];
#pragma unroll
    for (int i = 0; i < 10; ++i) insert10(t, P[4 + i]);
  }

  // lse_p: any positives <=> sp > 0 (each pos term >= exp(-40.96) > 0)
  float lse_p = (sp > 0.f) ? (C_OFF + __logf(sp)) : 0.f;
  float lse_n_all = (sn > 0.f) ? (C_OFF + __logf(sn)) : NEG_INF;

  // top-10 logsumexp (pads -1e30 -> alpha 0 -> logit -0; only used if nn>20
  // in which case all 10 are real)
  float mx = NEG_INF;
  float lg[10];
#pragma unroll
  for (int i = 0; i < 10; ++i) {
    float v = t[i];
    float a = fmaxf(v - 0.2f, 0.f);
    float lo = a * (v - 0.2f) * 64.f;
    lg[i] = lo;
    mx = fmaxf(mx, lo);
  }
  float ss = 0.f;
#pragma unroll
  for (int i = 0; i < 10; ++i) ss += __expf(lg[i] - mx);
  float lse_n_top = mx + __logf(ss);

  float lse_n = (nnf > 20.5f) ? lse_n_top : lse_n_all;
  float x = lse_n + lse_p;
  float loss = fmaxf(x, 0.f) + log1pf(__expf(-fabsf(x)));

  loss = wave_sum_f(loss);
  __shared__ float ws[4];
  if ((r & 63) == 0) ws[r >> 6] = loss;
  __syncthreads();
  if (r == 0) out[0] = (ws[0] + ws[1] + ws[2] + ws[3]) * (1.0f / 256.0f);
}

extern "C" void kernel_launch(void* const* d_in, const int* in_sizes, int n_in,
                              void* d_out, int out_size, void* d_ws, size_t ws_size,
                              hipStream_t stream) {
  const float* sim = (const float*)d_in[0];
  const float* label = (const float*)d_in[1];
  float* out = (float*)d_out;
  float* partials = (float*)d_ws;  // NBLOCKS * PSTRIDE floats = 64 KB
  ranking_partial_kernel<<<dim3(NBLOCKS), dim3(THREADS), 0, stream>>>(sim, label, partials);
  final_kernel<<<dim3(1), dim3(256), 0, stream>>>(partials, out);
}